// Round 22
// baseline (445.108 us; speedup 1.0000x reference)
//
#include <hip/hip_runtime.h>
#include <hip/hip_bf16.h>

// Qwen2 attention layer, MI355X/gfx950.
// B=2 S=2048 HID=3584 NH=28 NKV=4 D=128, causal, GQA groups=7.
// Round 22 = round 21 (440.2 us) + two ILP cuts:
//  - gemm256: next-tile bfr-c0 ds_reads moved from phase 0 to phase 3
//    (after vmcnt+barrier, buffer kt+1 fully valid; bfr c0 regs dead after
//    phase 2) -> read balance 8/4/8/4, reads overlap q3 MFMA.
//  - attn: softmax sum as 4 parallel chains (serial 16-add chain removed).
//
// Workspace layout (bytes), total ~99.5 MB:
//   Xb    @ 0          29,360,128  (B*S x HID bf16)      -> reused as AOb
//   Wcat  @ 29,360,128 33,030,144  (4608 x 3584 bf16)    -> reused as Wo-bf16
//   bcat  @ 62,390,272 18,432      (4608 f32)
//   QKVb  @ 62,408,704 37,748,736  (B*S x 4608 bf16)
//   Vt    @ 100,157,440 4,194,304  (B*NKV*128 x S bf16)

#define HID   3584
#define NHQ   28
#define NKVH  4
#define HD    128
#define SEQ   2048
#define NQKV  4608
#define GRP   7

typedef __attribute__((ext_vector_type(8))) short bf16x8;
typedef __attribute__((ext_vector_type(4))) float f32x4;
typedef __attribute__((ext_vector_type(16))) float f32x16;
typedef __attribute__((ext_vector_type(4))) int int4v;

#define BARRIER() asm volatile("s_barrier" ::: "memory")
#define LGKM0_FENCE() do { \
    asm volatile("s_waitcnt lgkmcnt(0)" ::: "memory"); \
    __builtin_amdgcn_sched_barrier(0); \
  } while (0)

__device__ __forceinline__ void gload_lds16(const void* g, void* l) {
  __builtin_amdgcn_global_load_lds(
      (const __attribute__((address_space(1))) void*)g,
      (__attribute__((address_space(3))) void*)l, 16, 0, 0);
}

__device__ __forceinline__ unsigned short f2bf(float f) {
  __hip_bfloat16 h = __float2bfloat16(f);
  return *reinterpret_cast<unsigned short*>(&h);
}

__device__ __forceinline__ float bf2f(unsigned short u) {
  __hip_bfloat16 h = *reinterpret_cast<__hip_bfloat16*>(&u);
  return __bfloat162float(h);
}

// ------ fused f32->bf16 conversion (X, Wq, Wk, Wv) + bias concat -----------
__global__ __launch_bounds__(256)
void cvt_fused(const float* __restrict__ X, const float* __restrict__ Wq,
               const float* __restrict__ Wk, const float* __restrict__ Wv,
               const float* __restrict__ bq, const float* __restrict__ bk,
               const float* __restrict__ bv,
               __hip_bfloat16* __restrict__ Xb, __hip_bfloat16* __restrict__ Wcat,
               float* __restrict__ bcat) {
  if (blockIdx.x >= 30464) {   // bias tail: 18 blocks
    int i = (blockIdx.x - 30464) * 256 + threadIdx.x;
    if (i < HID) bcat[i] = bq[i];
    else if (i < HID + 512) bcat[i] = bk[i - HID];
    else if (i < NQKV) bcat[i] = bv[i - HID - 512];
    return;
  }
  int i = blockIdx.x * 256 + threadIdx.x;   // 0 .. 7,798,783 (f32x4 units)
  const float* src;
  __hip_bfloat16* dst;
  int off;
  if (i < 3670016)      { src = X;  dst = Xb;   off = i; }
  else if (i < 6881280) { src = Wq; dst = Wcat; off = i - 3670016; }
  else if (i < 7340032) { src = Wk; dst = Wcat + (size_t)3584 * 3584; off = i - 6881280; }
  else                  { src = Wv; dst = Wcat + (size_t)4096 * 3584; off = i - 7340032; }
  float4 v = ((const float4*)src)[off];
  ushort4 o;
  o.x = f2bf(v.x); o.y = f2bf(v.y); o.z = f2bf(v.z); o.w = f2bf(v.w);
  ((ushort4*)dst)[off] = o;
}

// ---------------- GEMM 256^2: C[M][N](ldc) = A[M][K] * B[N][K]^T (+bias) ---
// n-fastest wgid; read balance 8/4/8/4 (bfr-c0 prefetched in phase 3).
template<bool HAS_BIAS, bool OUT_BF16>
__global__ __launch_bounds__(512, 2)
void gemm256(const __hip_bfloat16* __restrict__ A, const __hip_bfloat16* __restrict__ Bm,
             const float* __restrict__ bias, void* __restrict__ Cv,
             int M, int N, int K, int nnt, int ldc) {
  __shared__ __align__(16) char lds[131072];
  const int tid = threadIdx.x;
  const int w = tid >> 6, l = tid & 63;
  const int g = l >> 4, r = l & 15;
  const int wr = w >> 2, wc = w & 3;

  const int nwg = gridDim.x;
  const int qq = nwg >> 3, r8 = nwg & 7;
  const int xcd = blockIdx.x & 7, idx = blockIdx.x >> 3;
  const int wgid = (xcd < r8 ? xcd * (qq + 1) : r8 * (qq + 1) + (xcd - r8) * qq) + idx;
  const int bn = (wgid % nnt) * 256, bm = (wgid / nnt) * 256;

  const int NKT = K >> 6;
  const size_t Kb2 = (size_t)K * 2;
  const int swz = (r & 7) << 4;

  auto issueHalf = [&](int kt, int h) {
    const char* src = (h < 2) ? (const char*)A : (const char*)Bm;
    const int rbase = (h < 2) ? bm : bn;
    char* reg = lds + (kt & 1) * 65536 + ((h < 2) ? 0 : 32768);
#pragma unroll
    for (int i = 0; i < 2; ++i) {
      const int lrow = (h & 1) * 128 + w * 16 + i * 8;
      const int row = lrow + (l >> 3);
      const int cb = (l & 7) * 16;
      gload_lds16(src + (size_t)(rbase + row) * Kb2 + (size_t)kt * 128 + (cb ^ ((row & 7) << 4)),
                  reg + lrow * 128);
    }
  };

  auto ldA = [&](int d, int mf, int kk) -> bf16x8 {
    const int row = wr * 128 + mf * 16 + r;
    return *(const bf16x8*)(lds + d * 65536 + row * 128 + ((kk * 64 + g * 16) ^ swz));
  };
  auto ldB = [&](int d, int nf, int kk) -> bf16x8 {
    const int row = wc * 64 + nf * 16 + r;
    return *(const bf16x8*)(lds + d * 65536 + 32768 + row * 128 + ((kk * 64 + g * 16) ^ swz));
  };

  f32x4 acc[8][4];
#pragma unroll
  for (int m = 0; m < 8; m++)
#pragma unroll
    for (int n = 0; n < 4; n++) acc[m][n] = (f32x4){0.f, 0.f, 0.f, 0.f};

#pragma unroll
  for (int h = 0; h < 4; ++h) issueHalf(0, h);
#pragma unroll
  for (int h = 0; h < 4; ++h) issueHalf(1, h);
  asm volatile("s_waitcnt vmcnt(8)" ::: "memory");
  BARRIER();

  bf16x8 af[4][2], bfr[4][2];

  // prologue: bfr c0 of kt=0 (buffer 0 valid)
#pragma unroll
  for (int nf = 0; nf < 2; nf++)
#pragma unroll
    for (int kk = 0; kk < 2; kk++) bfr[nf][kk] = ldB(0, nf, kk);

#pragma unroll 1
  for (int kt = 0; kt < NKT; ++kt) {
    const int d = kt & 1;

    // ---- phase 0: stage kt+1 hi-halves; read A r0 (bfr c0 pre-read)
    if (kt >= 1 && kt + 1 < NKT) { issueHalf(kt + 1, 1); issueHalf(kt + 1, 3); }
#pragma unroll
    for (int mf = 0; mf < 4; mf++)
#pragma unroll
      for (int kk = 0; kk < 2; kk++) af[mf][kk] = ldA(d, mf, kk);
    BARRIER();
    LGKM0_FENCE();
    __builtin_amdgcn_s_setprio(1);
#pragma unroll
    for (int mf = 0; mf < 4; mf++)
#pragma unroll
      for (int nf = 0; nf < 2; nf++)
#pragma unroll
        for (int kk = 0; kk < 2; kk++)
          acc[mf][nf] = __builtin_amdgcn_mfma_f32_16x16x32_bf16(af[mf][kk], bfr[nf][kk], acc[mf][nf], 0, 0, 0);
    __builtin_amdgcn_s_setprio(0);
    BARRIER();

    // ---- phase 1: read B c1; MFMA q1
#pragma unroll
    for (int nf = 2; nf < 4; nf++)
#pragma unroll
      for (int kk = 0; kk < 2; kk++) bfr[nf][kk] = ldB(d, nf, kk);
    BARRIER();
    LGKM0_FENCE();
    __builtin_amdgcn_s_setprio(1);
#pragma unroll
    for (int mf = 0; mf < 4; mf++)
#pragma unroll
      for (int nf = 2; nf < 4; nf++)
#pragma unroll
        for (int kk = 0; kk < 2; kk++)
          acc[mf][nf] = __builtin_amdgcn_mfma_f32_16x16x32_bf16(af[mf][kk], bfr[nf][kk], acc[mf][nf], 0, 0, 0);
    __builtin_amdgcn_s_setprio(0);
    BARRIER();

    // ---- phase 2: stage kt+2 B-lo; read A r1; MFMA q2
    if (kt + 2 < NKT) issueHalf(kt + 2, 2);
#pragma unroll
    for (int mf = 0; mf < 4; mf++)
#pragma unroll
      for (int kk = 0; kk < 2; kk++) af[mf][kk] = ldA(d, mf + 4, kk);
    BARRIER();
    LGKM0_FENCE();
    __builtin_amdgcn_s_setprio(1);
#pragma unroll
    for (int mf = 0; mf < 4; mf++)
#pragma unroll
      for (int nf = 0; nf < 2; nf++)
#pragma unroll
        for (int kk = 0; kk < 2; kk++)
          acc[mf + 4][nf] = __builtin_amdgcn_mfma_f32_16x16x32_bf16(af[mf][kk], bfr[nf][kk], acc[mf + 4][nf], 0, 0, 0);
    __builtin_amdgcn_s_setprio(0);
    BARRIER();

    // ---- phase 3: stage kt+2 A-lo; counted vmcnt; prefetch kt+1 bfr c0;
    //      MFMA q3 (uses af r1 + bfr c1 only)
    if (kt + 2 < NKT) {
      issueHalf(kt + 2, 0);
      asm volatile("s_waitcnt vmcnt(4)" ::: "memory");
    } else if (kt + 1 < NKT) {
      asm volatile("s_waitcnt vmcnt(0)" ::: "memory");
    }
    BARRIER();
    if (kt + 1 < NKT) {   // buffer kt+1 fully valid; bfr c0 regs dead
#pragma unroll
      for (int nf = 0; nf < 2; nf++)
#pragma unroll
        for (int kk = 0; kk < 2; kk++) bfr[nf][kk] = ldB(d ^ 1, nf, kk);
    }
    __builtin_amdgcn_s_setprio(1);
#pragma unroll
    for (int mf = 0; mf < 4; mf++)
#pragma unroll
      for (int nf = 2; nf < 4; nf++)
#pragma unroll
        for (int kk = 0; kk < 2; kk++)
          acc[mf + 4][nf] = __builtin_amdgcn_mfma_f32_16x16x32_bf16(af[mf][kk], bfr[nf][kk], acc[mf + 4][nf], 0, 0, 0);
    __builtin_amdgcn_s_setprio(0);
    BARRIER();
  }

#pragma unroll
  for (int nf = 0; nf < 4; nf++) {
    const int gcol = bn + wc * 64 + nf * 16 + r;
    const float bv = HAS_BIAS ? bias[gcol] : 0.f;
#pragma unroll
    for (int mf = 0; mf < 8; mf++) {
#pragma unroll
      for (int j = 0; j < 4; j++) {
        const int grow = bm + wr * 128 + mf * 16 + 4 * g + j;
        float v = acc[mf][nf][j] + bv;
        if constexpr (OUT_BF16)
          ((__hip_bfloat16*)Cv)[(size_t)grow * ldc + gcol] = __float2bfloat16(v);
        else
          ((float*)Cv)[(size_t)grow * ldc + gcol] = v;
      }
    }
  }
}

// ------ V-projection (128^2 gemm_bt tiles) + RoPE, fused one launch --------
__global__ __launch_bounds__(256)
void vproj_rope(const __hip_bfloat16* __restrict__ Xb, const __hip_bfloat16* __restrict__ Wv_b,
                const float* __restrict__ bias_v, __hip_bfloat16* __restrict__ QKVb,
                const float* __restrict__ cosb, const float* __restrict__ sinb) {
  __shared__ __align__(16) __hip_bfloat16 As[128 * 32];
  __shared__ __align__(16) __hip_bfloat16 Bs[128 * 32];
  if (blockIdx.x < 128) {
    const int tid = threadIdx.x;
    const int w = tid >> 6, l = tid & 63;
    const int g = l >> 4, r = l & 15;
    const int wr = w >> 1, wc = w & 1;
    const int bm = (blockIdx.x & 31) * 128;
    const int bn = (blockIdx.x >> 5) * 128;
    const int lr = l >> 2;
    const int lc = (l & 3) * 8;

    f32x4 acc[4][4];
#pragma unroll
    for (int m = 0; m < 4; m++)
#pragma unroll
      for (int n = 0; n < 4; n++) acc[m][n] = (f32x4){0.f, 0.f, 0.f, 0.f};

    for (int k0 = 0; k0 < HID; k0 += 32) {
#pragma unroll
      for (int i = 0; i < 2; i++) {
        const int rb = w * 32 + i * 16;
        gload_lds16(&Xb[(size_t)(bm + rb + lr) * HID + k0 + lc], &As[rb * 32]);
        gload_lds16(&Wv_b[(size_t)(bn + rb + lr) * HID + k0 + lc], &Bs[rb * 32]);
      }
      __syncthreads();
      bf16x8 af[4], bfr[4];
#pragma unroll
      for (int m = 0; m < 4; m++) af[m] = *(const bf16x8*)&As[(wr * 64 + m * 16 + r) * 32 + g * 8];
#pragma unroll
      for (int n = 0; n < 4; n++) bfr[n] = *(const bf16x8*)&Bs[(wc * 64 + n * 16 + r) * 32 + g * 8];
#pragma unroll
      for (int m = 0; m < 4; m++)
#pragma unroll
        for (int n = 0; n < 4; n++)
          acc[m][n] = __builtin_amdgcn_mfma_f32_16x16x32_bf16(af[m], bfr[n], acc[m][n], 0, 0, 0);
      __syncthreads();
    }

#pragma unroll
    for (int m = 0; m < 4; m++) {
#pragma unroll
      for (int n = 0; n < 4; n++) {
        const int gcol = bn + wc * 64 + n * 16 + r;
        const float bv = bias_v[gcol];
#pragma unroll
        for (int j = 0; j < 4; j++) {
          const int grow = bm + wr * 64 + m * 16 + 4 * g + j;
          QKVb[(size_t)grow * NQKV + 4096 + gcol] = __float2bfloat16(acc[m][n][j] + bv);
        }
      }
    }
  } else {
    int i = (blockIdx.x - 128) * 256 + threadIdx.x;
    int d = (i & 15) * 4;
    int hh = (i >> 4) & 31;
    int row = i >> 9;
    int cb = (hh < NHQ) ? hh * HD : HID + (hh - NHQ) * HD;
    const float qs = (hh < NHQ) ? 0.12751744055204955f : 1.0f;
    unsigned short* base = (unsigned short*)QKVb + (size_t)row * NQKV + cb;
    float4 c = *(const float4*)&cosb[row * HD + d];
    float4 sn = *(const float4*)&sinb[row * HD + d];
    ushort4 u1 = *(const ushort4*)(base + d);
    ushort4 u2 = *(const ushort4*)(base + d + 64);
    float x1[4] = {bf2f(u1.x), bf2f(u1.y), bf2f(u1.z), bf2f(u1.w)};
    float x2[4] = {bf2f(u2.x), bf2f(u2.y), bf2f(u2.z), bf2f(u2.w)};
    float cc[4] = {c.x, c.y, c.z, c.w};
    float ss[4] = {sn.x, sn.y, sn.z, sn.w};
    ushort4 o1, o2;
    o1.x = f2bf((x1[0] * cc[0] - x2[0] * ss[0]) * qs); o2.x = f2bf((x2[0] * cc[0] + x1[0] * ss[0]) * qs);
    o1.y = f2bf((x1[1] * cc[1] - x2[1] * ss[1]) * qs); o2.y = f2bf((x2[1] * cc[1] + x1[1] * ss[1]) * qs);
    o1.z = f2bf((x1[2] * cc[2] - x2[2] * ss[2]) * qs); o2.z = f2bf((x2[2] * cc[2] + x1[2] * ss[2]) * qs);
    o1.w = f2bf((x1[3] * cc[3] - x2[3] * ss[3]) * qs); o2.w = f2bf((x2[3] * cc[3] + x1[3] * ss[3]) * qs);
    *(ushort4*)(base + d) = o1;
    *(ushort4*)(base + d + 64) = o2;
  }
}

// ------ V transpose + Wo conversion, fused ---------------------------------
__global__ __launch_bounds__(256)
void vt_wocvt(const __hip_bfloat16* __restrict__ QKV, __hip_bfloat16* __restrict__ Vt,
              const float* __restrict__ Wo, __hip_bfloat16* __restrict__ Wob) {
  __shared__ ushort tile[64][136];
  if (blockIdx.x < 256) {
    const int bx = blockIdx.x;
    const int st = bx & 31, kv = (bx >> 5) & 3, b = bx >> 7;
    const int s0 = st * 64;
    const int t = threadIdx.x;
    const int sl = t >> 4, dv = (t & 15) * 8;
    const ushort* src = (const ushort*)QKV + (size_t)(b * SEQ) * NQKV + HID + 512 + kv * HD;
#pragma unroll
    for (int p = 0; p < 4; p++) {
      const int s = s0 + p * 16 + sl;
      *(uint4*)&tile[p * 16 + sl][dv] = *(const uint4*)&src[(size_t)s * NQKV + dv];
    }
    __syncthreads();
    ushort* dst = (ushort*)Vt + (size_t)((b * NKVH + kv) * HD) * SEQ;
#pragma unroll
    for (int it = 0; it < 8; it++) {
      const int idx = it * 256 + t;
      const int d = idx >> 4, sg = idx & 15;
      ushort4 o;
      o.x = tile[sg * 4 + 0][d];
      o.y = tile[sg * 4 + 1][d];
      o.z = tile[sg * 4 + 2][d];
      o.w = tile[sg * 4 + 3][d];
      *(ushort4*)&dst[(size_t)d * SEQ + s0 + sg * 4] = o;
    }
  } else {
    int off = (blockIdx.x - 256) * 256 + threadIdx.x;   // < 3,211,264
    float4 v = ((const float4*)Wo)[off];
    ushort4 o;
    o.x = f2bf(v.x); o.y = f2bf(v.y); o.z = f2bf(v.z); o.w = f2bf(v.w);
    ((ushort4*)Wob)[off] = o;
  }
}

// ---------------- Flash attention (r21 body + 4-chain softmax sum) ---------
__global__ __launch_bounds__(256, 2)
void attn_fwd(const __hip_bfloat16* __restrict__ QKV, const __hip_bfloat16* __restrict__ Vt,
              __hip_bfloat16* __restrict__ AO) {
  const int head = blockIdx.x >> 1;
  const int b = blockIdx.x & 1;
  const int qb = 15 - blockIdx.y;           // LPT
  const int kvh = head / GRP;
  const int tid = threadIdx.x;
  const int w = tid >> 6, l = tid & 63;
  const int q32 = l & 31;
  const int hf = l >> 5;
  const int qw = qb * 128 + w * 32;
  const float NEGINF = -__builtin_inff();

  __shared__ __align__(16) __hip_bfloat16 Ks[2][64 * 128];
  __shared__ __align__(16) __hip_bfloat16 Vs[2][128 * 64];

  const char* Kb = (const char*)(QKV + (size_t)(b * SEQ) * NQKV + HID + kvh * HD);
  const char* Vb = (const char*)(Vt + (size_t)((b * NKVH + kvh) * HD) * SEQ);
  const __hip_bfloat16* Qb = QKV + (size_t)(b * SEQ + qw) * NQKV + head * HD;

  bf16x8 qf[8];
#pragma unroll
  for (int c = 0; c < 8; c++)
    qf[c] = *(const bf16x8*)&Qb[(size_t)q32 * NQKV + c * 16 + 8 * hf];

  f32x16 of[4] = {};
  float mrow = -3e38f, lsum = 0.f;

  const int ntiles = 2 * qb + 2;

  auto stage = [&](int buf, int kv0) {
#pragma unroll
    for (int p = 0; p < 4; p++) {
      const int row = w * 16 + p * 4 + (l >> 4);
      const int cb = (l & 15) * 16;
      gload_lds16(Kb + (size_t)(kv0 + row) * (NQKV * 2) + (cb ^ ((row & 7) << 4)),
                  (char*)(Ks[buf]) + w * 4096 + p * 1024);
    }
#pragma unroll
    for (int p = 0; p < 4; p++) {
      const int row = w * 32 + p * 8 + (l >> 3);
      const int cb = (l & 7) * 16;
      gload_lds16(Vb + (size_t)row * (SEQ * 2) + (size_t)kv0 * 2 + (cb ^ ((row & 7) << 4)),
                  (char*)(Vs[buf]) + w * 4096 + p * 1024);
    }
  };

  stage(0, 0);
  __syncthreads();

  const int swz = (q32 & 7) << 4;
  const int qg = qw + q32;

  for (int t = 0; t < ntiles; t++) {
    const int cur = t & 1;
    if (t + 1 < ntiles) stage(cur ^ 1, t * 64 + 64);

#pragma unroll
    for (int half = 0; half < 2; half++) {
      const int kv0 = t * 64 + half * 32;
      if (kv0 <= qw + 31) {
        f32x16 s = {};
        const char* kb = (const char*)(Ks[cur]) + (half * 32 + q32) * 256;
        __builtin_amdgcn_s_setprio(1);
#pragma unroll
        for (int c = 0; c < 8; c++) {
          bf16x8 kf = *(const bf16x8*)(kb + ((c * 32 + 16 * hf) ^ swz));
          s = __builtin_amdgcn_mfma_f32_32x32x16_bf16(kf, qf[c], s, 0, 0, 0);
        }
        __builtin_amdgcn_s_setprio(0);

        if (!(kv0 + 31 <= qw)) {
#pragma unroll
          for (int j = 0; j < 16; j++) {
            const int kvl = (j & 3) + 8 * (j >> 2) + 4 * hf;
            s[j] = (kv0 + kvl <= qg) ? s[j] : NEGINF;
          }
        }
        float m0 = fmaxf(s[0], s[4]), m1 = fmaxf(s[1], s[5]);
        float m2 = fmaxf(s[2], s[6]), m3 = fmaxf(s[3], s[7]);
        m0 = fmaxf(m0, fmaxf(s[8], s[12]));  m1 = fmaxf(m1, fmaxf(s[9], s[13]));
        m2 = fmaxf(m2, fmaxf(s[10], s[14])); m3 = fmaxf(m3, fmaxf(s[11], s[15]));
        float pmax = fmaxf(fmaxf(m0, m1), fmaxf(m2, m3));
        pmax = fmaxf(pmax, __shfl_xor(pmax, 32));

        float r0 = 0.f, r1 = 0.f, r2 = 0.f, r3 = 0.f;
        if (__all(pmax - mrow <= 11.5f)) {
#pragma unroll
          for (int j = 0; j < 16; j += 4) {
            float p0 = exp2f(s[j + 0] - mrow); s[j + 0] = p0; r0 += p0;
            float p1 = exp2f(s[j + 1] - mrow); s[j + 1] = p1; r1 += p1;
            float p2 = exp2f(s[j + 2] - mrow); s[j + 2] = p2; r2 += p2;
            float p3 = exp2f(s[j + 3] - mrow); s[j + 3] = p3; r3 += p3;
          }
        } else {
          const float nm = fmaxf(mrow, pmax);
          const float al = exp2f(mrow - nm);
          mrow = nm;
#pragma unroll
          for (int j = 0; j < 16; j += 4) {
            float p0 = exp2f(s[j + 0] - nm); s[j + 0] = p0; r0 += p0;
            float p1 = exp2f(s[j + 1] - nm); s[j + 1] = p1; r1 += p1;
            float p2 = exp2f(s[j + 2] - nm); s[j + 2] = p2; r2 += p2;
            float p3 = exp2f(s[j + 3] - nm); s[j + 3] = p3; r3 += p3;
          }
          lsum *= al;
#pragma unroll
          for (int db = 0; db < 4; db++) of[db] *= al;
        }
        lsum += (r0 + r1) + (r2 + r3);

        int wv[8];
#pragma unroll
        for (int k = 0; k < 8; k++)
          wv[k] = (int)((unsigned)f2bf(s[2 * k]) | ((unsigned)f2bf(s[2 * k + 1]) << 16));

        {
          auto ra = __builtin_amdgcn_permlane32_swap(wv[0], wv[2], false, false);
          auto rb = __builtin_amdgcn_permlane32_swap(wv[1], wv[3], false, false);
          union { int4v i; bf16x8 h; } u;
          u.i = (int4v){(int)ra[0], (int)rb[0], (int)ra[1], (int)rb[1]};
          const bf16x8 pB = u.h;
          __builtin_amdgcn_s_setprio(1);
#pragma unroll
          for (int db = 0; db < 4; db++) {
            const char* vp = (const char*)(Vs[cur]) + (db * 32 + q32) * 128;
            bf16x8 vf = *(const bf16x8*)(vp + ((half * 64 + 0 + 16 * hf) ^ swz));
            of[db] = __builtin_amdgcn_mfma_f32_32x32x16_bf16(vf, pB, of[db], 0, 0, 0);
          }
          __builtin_amdgcn_s_setprio(0);
        }
        {
          auto rc = __builtin_amdgcn_permlane32_swap(wv[4], wv[6], false, false);
          auto rd = __builtin_amdgcn_permlane32_swap(wv[5], wv[7], false, false);
          union { int4v i; bf16x8 h; } u2;
          u2.i = (int4v){(int)rc[0], (int)rd[0], (int)rc[1], (int)rd[1]};
          const bf16x8 pB = u2.h;
          __builtin_amdgcn_s_setprio(1);
#pragma unroll
          for (int db = 0; db < 4; db++) {
            const char* vp = (const char*)(Vs[cur]) + (db * 32 + q32) * 128;
            bf16x8 vf = *(const bf16x8*)(vp + ((half * 64 + 32 + 16 * hf) ^ swz));
            of[db] = __builtin_amdgcn_mfma_f32_32x32x16_bf16(vf, pB, of[db], 0, 0, 0);
          }
          __builtin_amdgcn_s_setprio(0);
        }
      }
    }
    if (t + 1 < ntiles) __syncthreads();
  }

  const float ltot = lsum + __shfl_xor(lsum, 32);
  unsigned short* AOu = (unsigned short*)AO;
  const float inv = 1.0f / ltot;
  const size_t rowb = (size_t)(b * SEQ + qw + q32) * HID + head * HD;
#pragma unroll
  for (int db = 0; db < 4; db++) {
#pragma unroll
    for (int qd = 0; qd < 4; qd++) {
      ushort4 o;
      o.x = f2bf(of[db][4 * qd + 0] * inv);
      o.y = f2bf(of[db][4 * qd + 1] * inv);
      o.z = f2bf(of[db][4 * qd + 2] * inv);
      o.w = f2bf(of[db][4 * qd + 3] * inv);
      *(ushort4*)&AOu[rowb + db * 32 + 8 * qd + 4 * hf] = o;
    }
  }
}

// ---------------------------------------------------------------------------
extern "C" void kernel_launch(void* const* d_in, const int* in_sizes, int n_in,
                              void* d_out, int out_size, void* d_ws, size_t ws_size,
                              hipStream_t stream) {
  const float* hs = (const float*)d_in[0];
  const float* cosb = (const float*)d_in[1];
  const float* sinb = (const float*)d_in[2];
  const float* Wq = (const float*)d_in[3];
  const float* bq = (const float*)d_in[4];
  const float* Wk = (const float*)d_in[5];
  const float* bk = (const float*)d_in[6];
  const float* Wv = (const float*)d_in[7];
  const float* bv = (const float*)d_in[8];
  const float* Wo = (const float*)d_in[9];

  char* ws = (char*)d_ws;
  __hip_bfloat16* Xb = (__hip_bfloat16*)(ws);
  __hip_bfloat16* Wcat = (__hip_bfloat16*)(ws + 29360128);
  float* bcat = (float*)(ws + 62390272);
  __hip_bfloat16* QKVb = (__hip_bfloat16*)(ws + 62408704);
  __hip_bfloat16* Vt = (__hip_bfloat16*)(ws + 100157440);
  __hip_bfloat16* AOb = Xb;    // X dead after projections
  __hip_bfloat16* Wob = Wcat;  // Wq/Wk rows dead after QK GEMM

  // Fused conversions (X, Wq, Wk, Wv) + bias concat (tail blocks)
  cvt_fused<<<30482, 256, 0, stream>>>(hs, Wq, Wk, Wv, bq, bk, bv, Xb, Wcat, bcat);

  // QK projection: [4096 x 4096] -> QKVb cols 0..4095. 256 blocks = 1 round.
  gemm256<true, true><<<256, 512, 0, stream>>>(Xb, Wcat, bcat, QKVb,
                                               4096, 4096, HID, 16, NQKV);

  // V projection (128 blocks) + RoPE (8192 blocks), one launch.
  vproj_rope<<<8320, 256, 0, stream>>>(Xb, Wcat + (size_t)4096 * 3584,
                                       bcat + 4096, QKVb, cosb, sinb);

  // V transpose (256 blocks) + Wo conversion, one launch.
  vt_wocvt<<<12800, 256, 0, stream>>>(QKVb, Vt, Wo, Wob);

  // Flash attention
  dim3 ga(56, 16);
  attn_fwd<<<ga, 256, 0, stream>>>(QKVb, Vt, AOb);

  // O projection -> f32 out (224 blocks; nnt=14 -> whole-m-row XCD chunks)
  gemm256<false, false><<<224, 512, 0, stream>>>(AOb, Wob, nullptr, d_out,
                                                 4096, HID, HID, 14, HID);
}

// Round 23
// 440.076 us; speedup vs baseline: 1.0114x; 1.0114x over previous
//
#include <hip/hip_runtime.h>
#include <hip/hip_bf16.h>

// Qwen2 attention layer, MI355X/gfx950.
// B=2 S=2048 HID=3584 NH=28 NKV=4 D=128, causal, GQA groups=7.
// Round 23 = exact restore of round 21 (proven best: 440.2 us).
// r22's two micro-reorderings (4-chain softmax sum, gemm256 phase-3 bfr
// prefetch) both regressed (445.1; attn VGPR 124->128) -> reverted.
// Third confirmation that this kernel set is at a schedule-local optimum
// for compiler-visible reorderings.
//
// Workspace layout (bytes), total ~99.5 MB:
//   Xb    @ 0          29,360,128  (B*S x HID bf16)      -> reused as AOb
//   Wcat  @ 29,360,128 33,030,144  (4608 x 3584 bf16)    -> reused as Wo-bf16
//   bcat  @ 62,390,272 18,432      (4608 f32)
//   QKVb  @ 62,408,704 37,748,736  (B*S x 4608 bf16)
//   Vt    @ 100,157,440 4,194,304  (B*NKV*128 x S bf16)

#define HID   3584
#define NHQ   28
#define NKVH  4
#define HD    128
#define SEQ   2048
#define NQKV  4608
#define GRP   7

typedef __attribute__((ext_vector_type(8))) short bf16x8;
typedef __attribute__((ext_vector_type(4))) float f32x4;
typedef __attribute__((ext_vector_type(16))) float f32x16;
typedef __attribute__((ext_vector_type(4))) int int4v;

#define BARRIER() asm volatile("s_barrier" ::: "memory")
#define LGKM0_FENCE() do { \
    asm volatile("s_waitcnt lgkmcnt(0)" ::: "memory"); \
    __builtin_amdgcn_sched_barrier(0); \
  } while (0)

__device__ __forceinline__ void gload_lds16(const void* g, void* l) {
  __builtin_amdgcn_global_load_lds(
      (const __attribute__((address_space(1))) void*)g,
      (__attribute__((address_space(3))) void*)l, 16, 0, 0);
}

__device__ __forceinline__ unsigned short f2bf(float f) {
  __hip_bfloat16 h = __float2bfloat16(f);
  return *reinterpret_cast<unsigned short*>(&h);
}

__device__ __forceinline__ float bf2f(unsigned short u) {
  __hip_bfloat16 h = *reinterpret_cast<__hip_bfloat16*>(&u);
  return __bfloat162float(h);
}

// ------ fused f32->bf16 conversion (X, Wq, Wk, Wv) + bias concat -----------
__global__ __launch_bounds__(256)
void cvt_fused(const float* __restrict__ X, const float* __restrict__ Wq,
               const float* __restrict__ Wk, const float* __restrict__ Wv,
               const float* __restrict__ bq, const float* __restrict__ bk,
               const float* __restrict__ bv,
               __hip_bfloat16* __restrict__ Xb, __hip_bfloat16* __restrict__ Wcat,
               float* __restrict__ bcat) {
  if (blockIdx.x >= 30464) {   // bias tail: 18 blocks
    int i = (blockIdx.x - 30464) * 256 + threadIdx.x;
    if (i < HID) bcat[i] = bq[i];
    else if (i < HID + 512) bcat[i] = bk[i - HID];
    else if (i < NQKV) bcat[i] = bv[i - HID - 512];
    return;
  }
  int i = blockIdx.x * 256 + threadIdx.x;   // 0 .. 7,798,783 (f32x4 units)
  const float* src;
  __hip_bfloat16* dst;
  int off;
  if (i < 3670016)      { src = X;  dst = Xb;   off = i; }
  else if (i < 6881280) { src = Wq; dst = Wcat; off = i - 3670016; }
  else if (i < 7340032) { src = Wk; dst = Wcat + (size_t)3584 * 3584; off = i - 6881280; }
  else                  { src = Wv; dst = Wcat + (size_t)4096 * 3584; off = i - 7340032; }
  float4 v = ((const float4*)src)[off];
  ushort4 o;
  o.x = f2bf(v.x); o.y = f2bf(v.y); o.z = f2bf(v.z); o.w = f2bf(v.w);
  ((ushort4*)dst)[off] = o;
}

// ---------------- GEMM 256^2 (r20 body) ------------------------------------
template<bool HAS_BIAS, bool OUT_BF16>
__global__ __launch_bounds__(512, 2)
void gemm256(const __hip_bfloat16* __restrict__ A, const __hip_bfloat16* __restrict__ Bm,
             const float* __restrict__ bias, void* __restrict__ Cv,
             int M, int N, int K, int nnt, int ldc) {
  __shared__ __align__(16) char lds[131072];
  const int tid = threadIdx.x;
  const int w = tid >> 6, l = tid & 63;
  const int g = l >> 4, r = l & 15;
  const int wr = w >> 2, wc = w & 3;

  const int nwg = gridDim.x;
  const int qq = nwg >> 3, r8 = nwg & 7;
  const int xcd = blockIdx.x & 7, idx = blockIdx.x >> 3;
  const int wgid = (xcd < r8 ? xcd * (qq + 1) : r8 * (qq + 1) + (xcd - r8) * qq) + idx;
  const int bn = (wgid % nnt) * 256, bm = (wgid / nnt) * 256;

  const int NKT = K >> 6;
  const size_t Kb2 = (size_t)K * 2;
  const int swz = (r & 7) << 4;

  auto issueHalf = [&](int kt, int h) {
    const char* src = (h < 2) ? (const char*)A : (const char*)Bm;
    const int rbase = (h < 2) ? bm : bn;
    char* reg = lds + (kt & 1) * 65536 + ((h < 2) ? 0 : 32768);
#pragma unroll
    for (int i = 0; i < 2; ++i) {
      const int lrow = (h & 1) * 128 + w * 16 + i * 8;
      const int row = lrow + (l >> 3);
      const int cb = (l & 7) * 16;
      gload_lds16(src + (size_t)(rbase + row) * Kb2 + (size_t)kt * 128 + (cb ^ ((row & 7) << 4)),
                  reg + lrow * 128);
    }
  };

  auto ldA = [&](int d, int mf, int kk) -> bf16x8 {
    const int row = wr * 128 + mf * 16 + r;
    return *(const bf16x8*)(lds + d * 65536 + row * 128 + ((kk * 64 + g * 16) ^ swz));
  };
  auto ldB = [&](int d, int nf, int kk) -> bf16x8 {
    const int row = wc * 64 + nf * 16 + r;
    return *(const bf16x8*)(lds + d * 65536 + 32768 + row * 128 + ((kk * 64 + g * 16) ^ swz));
  };

  f32x4 acc[8][4];
#pragma unroll
  for (int m = 0; m < 8; m++)
#pragma unroll
    for (int n = 0; n < 4; n++) acc[m][n] = (f32x4){0.f, 0.f, 0.f, 0.f};

#pragma unroll
  for (int h = 0; h < 4; ++h) issueHalf(0, h);
#pragma unroll
  for (int h = 0; h < 4; ++h) issueHalf(1, h);
  asm volatile("s_waitcnt vmcnt(8)" ::: "memory");
  BARRIER();

  bf16x8 af[4][2], bfr[4][2];

#pragma unroll 1
  for (int kt = 0; kt < NKT; ++kt) {
    const int d = kt & 1;

    if (kt >= 1 && kt + 1 < NKT) { issueHalf(kt + 1, 1); issueHalf(kt + 1, 3); }
#pragma unroll
    for (int mf = 0; mf < 4; mf++)
#pragma unroll
      for (int kk = 0; kk < 2; kk++) af[mf][kk] = ldA(d, mf, kk);
#pragma unroll
    for (int nf = 0; nf < 2; nf++)
#pragma unroll
      for (int kk = 0; kk < 2; kk++) bfr[nf][kk] = ldB(d, nf, kk);
    BARRIER();
    LGKM0_FENCE();
    __builtin_amdgcn_s_setprio(1);
#pragma unroll
    for (int mf = 0; mf < 4; mf++)
#pragma unroll
      for (int nf = 0; nf < 2; nf++)
#pragma unroll
        for (int kk = 0; kk < 2; kk++)
          acc[mf][nf] = __builtin_amdgcn_mfma_f32_16x16x32_bf16(af[mf][kk], bfr[nf][kk], acc[mf][nf], 0, 0, 0);
    __builtin_amdgcn_s_setprio(0);
    BARRIER();

#pragma unroll
    for (int nf = 2; nf < 4; nf++)
#pragma unroll
      for (int kk = 0; kk < 2; kk++) bfr[nf][kk] = ldB(d, nf, kk);
    BARRIER();
    LGKM0_FENCE();
    __builtin_amdgcn_s_setprio(1);
#pragma unroll
    for (int mf = 0; mf < 4; mf++)
#pragma unroll
      for (int nf = 2; nf < 4; nf++)
#pragma unroll
        for (int kk = 0; kk < 2; kk++)
          acc[mf][nf] = __builtin_amdgcn_mfma_f32_16x16x32_bf16(af[mf][kk], bfr[nf][kk], acc[mf][nf], 0, 0, 0);
    __builtin_amdgcn_s_setprio(0);
    BARRIER();

    if (kt + 2 < NKT) issueHalf(kt + 2, 2);
#pragma unroll
    for (int mf = 0; mf < 4; mf++)
#pragma unroll
      for (int kk = 0; kk < 2; kk++) af[mf][kk] = ldA(d, mf + 4, kk);
    BARRIER();
    LGKM0_FENCE();
    __builtin_amdgcn_s_setprio(1);
#pragma unroll
    for (int mf = 0; mf < 4; mf++)
#pragma unroll
      for (int nf = 0; nf < 2; nf++)
#pragma unroll
        for (int kk = 0; kk < 2; kk++)
          acc[mf + 4][nf] = __builtin_amdgcn_mfma_f32_16x16x32_bf16(af[mf][kk], bfr[nf][kk], acc[mf + 4][nf], 0, 0, 0);
    __builtin_amdgcn_s_setprio(0);
    BARRIER();

    if (kt + 2 < NKT) {
      issueHalf(kt + 2, 0);
      asm volatile("s_waitcnt vmcnt(4)" ::: "memory");
    } else if (kt + 1 < NKT) {
      asm volatile("s_waitcnt vmcnt(0)" ::: "memory");
    }
    BARRIER();
    __builtin_amdgcn_s_setprio(1);
#pragma unroll
    for (int mf = 0; mf < 4; mf++)
#pragma unroll
      for (int nf = 2; nf < 4; nf++)
#pragma unroll
        for (int kk = 0; kk < 2; kk++)
          acc[mf + 4][nf] = __builtin_amdgcn_mfma_f32_16x16x32_bf16(af[mf][kk], bfr[nf][kk], acc[mf + 4][nf], 0, 0, 0);
    __builtin_amdgcn_s_setprio(0);
    BARRIER();
  }

#pragma unroll
  for (int nf = 0; nf < 4; nf++) {
    const int gcol = bn + wc * 64 + nf * 16 + r;
    const float bv = HAS_BIAS ? bias[gcol] : 0.f;
#pragma unroll
    for (int mf = 0; mf < 8; mf++) {
#pragma unroll
      for (int j = 0; j < 4; j++) {
        const int grow = bm + wr * 128 + mf * 16 + 4 * g + j;
        float v = acc[mf][nf][j] + bv;
        if constexpr (OUT_BF16)
          ((__hip_bfloat16*)Cv)[(size_t)grow * ldc + gcol] = __float2bfloat16(v);
        else
          ((float*)Cv)[(size_t)grow * ldc + gcol] = v;
      }
    }
  }
}

// ------ V-projection (128^2 gemm_bt tiles) + RoPE, fused one launch --------
__global__ __launch_bounds__(256)
void vproj_rope(const __hip_bfloat16* __restrict__ Xb, const __hip_bfloat16* __restrict__ Wv_b,
                const float* __restrict__ bias_v, __hip_bfloat16* __restrict__ QKVb,
                const float* __restrict__ cosb, const float* __restrict__ sinb) {
  __shared__ __align__(16) __hip_bfloat16 As[128 * 32];
  __shared__ __align__(16) __hip_bfloat16 Bs[128 * 32];
  if (blockIdx.x < 128) {
    const int tid = threadIdx.x;
    const int w = tid >> 6, l = tid & 63;
    const int g = l >> 4, r = l & 15;
    const int wr = w >> 1, wc = w & 1;
    const int bm = (blockIdx.x & 31) * 128;
    const int bn = (blockIdx.x >> 5) * 128;
    const int lr = l >> 2;
    const int lc = (l & 3) * 8;

    f32x4 acc[4][4];
#pragma unroll
    for (int m = 0; m < 4; m++)
#pragma unroll
      for (int n = 0; n < 4; n++) acc[m][n] = (f32x4){0.f, 0.f, 0.f, 0.f};

    for (int k0 = 0; k0 < HID; k0 += 32) {
#pragma unroll
      for (int i = 0; i < 2; i++) {
        const int rb = w * 32 + i * 16;
        gload_lds16(&Xb[(size_t)(bm + rb + lr) * HID + k0 + lc], &As[rb * 32]);
        gload_lds16(&Wv_b[(size_t)(bn + rb + lr) * HID + k0 + lc], &Bs[rb * 32]);
      }
      __syncthreads();
      bf16x8 af[4], bfr[4];
#pragma unroll
      for (int m = 0; m < 4; m++) af[m] = *(const bf16x8*)&As[(wr * 64 + m * 16 + r) * 32 + g * 8];
#pragma unroll
      for (int n = 0; n < 4; n++) bfr[n] = *(const bf16x8*)&Bs[(wc * 64 + n * 16 + r) * 32 + g * 8];
#pragma unroll
      for (int m = 0; m < 4; m++)
#pragma unroll
        for (int n = 0; n < 4; n++)
          acc[m][n] = __builtin_amdgcn_mfma_f32_16x16x32_bf16(af[m], bfr[n], acc[m][n], 0, 0, 0);
      __syncthreads();
    }

#pragma unroll
    for (int m = 0; m < 4; m++) {
#pragma unroll
      for (int n = 0; n < 4; n++) {
        const int gcol = bn + wc * 64 + n * 16 + r;
        const float bv = bias_v[gcol];
#pragma unroll
        for (int j = 0; j < 4; j++) {
          const int grow = bm + wr * 64 + m * 16 + 4 * g + j;
          QKVb[(size_t)grow * NQKV + 4096 + gcol] = __float2bfloat16(acc[m][n][j] + bv);
        }
      }
    }
  } else {
    int i = (blockIdx.x - 128) * 256 + threadIdx.x;
    int d = (i & 15) * 4;
    int hh = (i >> 4) & 31;
    int row = i >> 9;
    int cb = (hh < NHQ) ? hh * HD : HID + (hh - NHQ) * HD;
    const float qs = (hh < NHQ) ? 0.12751744055204955f : 1.0f;
    unsigned short* base = (unsigned short*)QKVb + (size_t)row * NQKV + cb;
    float4 c = *(const float4*)&cosb[row * HD + d];
    float4 sn = *(const float4*)&sinb[row * HD + d];
    ushort4 u1 = *(const ushort4*)(base + d);
    ushort4 u2 = *(const ushort4*)(base + d + 64);
    float x1[4] = {bf2f(u1.x), bf2f(u1.y), bf2f(u1.z), bf2f(u1.w)};
    float x2[4] = {bf2f(u2.x), bf2f(u2.y), bf2f(u2.z), bf2f(u2.w)};
    float cc[4] = {c.x, c.y, c.z, c.w};
    float ss[4] = {sn.x, sn.y, sn.z, sn.w};
    ushort4 o1, o2;
    o1.x = f2bf((x1[0] * cc[0] - x2[0] * ss[0]) * qs); o2.x = f2bf((x2[0] * cc[0] + x1[0] * ss[0]) * qs);
    o1.y = f2bf((x1[1] * cc[1] - x2[1] * ss[1]) * qs); o2.y = f2bf((x2[1] * cc[1] + x1[1] * ss[1]) * qs);
    o1.z = f2bf((x1[2] * cc[2] - x2[2] * ss[2]) * qs); o2.z = f2bf((x2[2] * cc[2] + x1[2] * ss[2]) * qs);
    o1.w = f2bf((x1[3] * cc[3] - x2[3] * ss[3]) * qs); o2.w = f2bf((x2[3] * cc[3] + x1[3] * ss[3]) * qs);
    *(ushort4*)(base + d) = o1;
    *(ushort4*)(base + d + 64) = o2;
  }
}

// ------ V transpose + Wo conversion, fused ---------------------------------
__global__ __launch_bounds__(256)
void vt_wocvt(const __hip_bfloat16* __restrict__ QKV, __hip_bfloat16* __restrict__ Vt,
              const float* __restrict__ Wo, __hip_bfloat16* __restrict__ Wob) {
  __shared__ ushort tile[64][136];
  if (blockIdx.x < 256) {
    const int bx = blockIdx.x;
    const int st = bx & 31, kv = (bx >> 5) & 3, b = bx >> 7;
    const int s0 = st * 64;
    const int t = threadIdx.x;
    const int sl = t >> 4, dv = (t & 15) * 8;
    const ushort* src = (const ushort*)QKV + (size_t)(b * SEQ) * NQKV + HID + 512 + kv * HD;
#pragma unroll
    for (int p = 0; p < 4; p++) {
      const int s = s0 + p * 16 + sl;
      *(uint4*)&tile[p * 16 + sl][dv] = *(const uint4*)&src[(size_t)s * NQKV + dv];
    }
    __syncthreads();
    ushort* dst = (ushort*)Vt + (size_t)((b * NKVH + kv) * HD) * SEQ;
#pragma unroll
    for (int it = 0; it < 8; it++) {
      const int idx = it * 256 + t;
      const int d = idx >> 4, sg = idx & 15;
      ushort4 o;
      o.x = tile[sg * 4 + 0][d];
      o.y = tile[sg * 4 + 1][d];
      o.z = tile[sg * 4 + 2][d];
      o.w = tile[sg * 4 + 3][d];
      *(ushort4*)&dst[(size_t)d * SEQ + s0 + sg * 4] = o;
    }
  } else {
    int off = (blockIdx.x - 256) * 256 + threadIdx.x;   // < 3,211,264
    float4 v = ((const float4*)Wo)[off];
    ushort4 o;
    o.x = f2bf(v.x); o.y = f2bf(v.y); o.z = f2bf(v.z); o.w = f2bf(v.w);
    ((ushort4*)Wob)[off] = o;
  }
}

// ---------------- Flash attention (r21 body) -------------------------------
__global__ __launch_bounds__(256, 2)
void attn_fwd(const __hip_bfloat16* __restrict__ QKV, const __hip_bfloat16* __restrict__ Vt,
              __hip_bfloat16* __restrict__ AO) {
  const int head = blockIdx.x >> 1;
  const int b = blockIdx.x & 1;
  const int qb = 15 - blockIdx.y;           // LPT
  const int kvh = head / GRP;
  const int tid = threadIdx.x;
  const int w = tid >> 6, l = tid & 63;
  const int q32 = l & 31;
  const int hf = l >> 5;
  const int qw = qb * 128 + w * 32;
  const float NEGINF = -__builtin_inff();

  __shared__ __align__(16) __hip_bfloat16 Ks[2][64 * 128];
  __shared__ __align__(16) __hip_bfloat16 Vs[2][128 * 64];

  const char* Kb = (const char*)(QKV + (size_t)(b * SEQ) * NQKV + HID + kvh * HD);
  const char* Vb = (const char*)(Vt + (size_t)((b * NKVH + kvh) * HD) * SEQ);
  const __hip_bfloat16* Qb = QKV + (size_t)(b * SEQ + qw) * NQKV + head * HD;

  bf16x8 qf[8];
#pragma unroll
  for (int c = 0; c < 8; c++)
    qf[c] = *(const bf16x8*)&Qb[(size_t)q32 * NQKV + c * 16 + 8 * hf];

  f32x16 of[4] = {};
  float mrow = -3e38f, lsum = 0.f;

  const int ntiles = 2 * qb + 2;

  auto stage = [&](int buf, int kv0) {
#pragma unroll
    for (int p = 0; p < 4; p++) {
      const int row = w * 16 + p * 4 + (l >> 4);
      const int cb = (l & 15) * 16;
      gload_lds16(Kb + (size_t)(kv0 + row) * (NQKV * 2) + (cb ^ ((row & 7) << 4)),
                  (char*)(Ks[buf]) + w * 4096 + p * 1024);
    }
#pragma unroll
    for (int p = 0; p < 4; p++) {
      const int row = w * 32 + p * 8 + (l >> 3);
      const int cb = (l & 7) * 16;
      gload_lds16(Vb + (size_t)row * (SEQ * 2) + (size_t)kv0 * 2 + (cb ^ ((row & 7) << 4)),
                  (char*)(Vs[buf]) + w * 4096 + p * 1024);
    }
  };

  stage(0, 0);
  __syncthreads();

  const int swz = (q32 & 7) << 4;
  const int qg = qw + q32;

  for (int t = 0; t < ntiles; t++) {
    const int cur = t & 1;
    if (t + 1 < ntiles) stage(cur ^ 1, t * 64 + 64);

#pragma unroll
    for (int half = 0; half < 2; half++) {
      const int kv0 = t * 64 + half * 32;
      if (kv0 <= qw + 31) {
        f32x16 s = {};
        const char* kb = (const char*)(Ks[cur]) + (half * 32 + q32) * 256;
        __builtin_amdgcn_s_setprio(1);
#pragma unroll
        for (int c = 0; c < 8; c++) {
          bf16x8 kf = *(const bf16x8*)(kb + ((c * 32 + 16 * hf) ^ swz));
          s = __builtin_amdgcn_mfma_f32_32x32x16_bf16(kf, qf[c], s, 0, 0, 0);
        }
        __builtin_amdgcn_s_setprio(0);

        if (!(kv0 + 31 <= qw)) {
#pragma unroll
          for (int j = 0; j < 16; j++) {
            const int kvl = (j & 3) + 8 * (j >> 2) + 4 * hf;
            s[j] = (kv0 + kvl <= qg) ? s[j] : NEGINF;
          }
        }
        float m0 = fmaxf(s[0], s[4]), m1 = fmaxf(s[1], s[5]);
        float m2 = fmaxf(s[2], s[6]), m3 = fmaxf(s[3], s[7]);
        m0 = fmaxf(m0, fmaxf(s[8], s[12]));  m1 = fmaxf(m1, fmaxf(s[9], s[13]));
        m2 = fmaxf(m2, fmaxf(s[10], s[14])); m3 = fmaxf(m3, fmaxf(s[11], s[15]));
        float pmax = fmaxf(fmaxf(m0, m1), fmaxf(m2, m3));
        pmax = fmaxf(pmax, __shfl_xor(pmax, 32));

        float rs = 0.f;
        if (__all(pmax - mrow <= 11.5f)) {
#pragma unroll
          for (int j = 0; j < 16; j++) { float p = exp2f(s[j] - mrow); s[j] = p; rs += p; }
        } else {
          const float nm = fmaxf(mrow, pmax);
          const float al = exp2f(mrow - nm);
          mrow = nm;
#pragma unroll
          for (int j = 0; j < 16; j++) { float p = exp2f(s[j] - nm); s[j] = p; rs += p; }
          lsum *= al;
#pragma unroll
          for (int db = 0; db < 4; db++) of[db] *= al;
        }
        lsum += rs;

        int wv[8];
#pragma unroll
        for (int k = 0; k < 8; k++)
          wv[k] = (int)((unsigned)f2bf(s[2 * k]) | ((unsigned)f2bf(s[2 * k + 1]) << 16));

        {
          auto ra = __builtin_amdgcn_permlane32_swap(wv[0], wv[2], false, false);
          auto rb = __builtin_amdgcn_permlane32_swap(wv[1], wv[3], false, false);
          union { int4v i; bf16x8 h; } u;
          u.i = (int4v){(int)ra[0], (int)rb[0], (int)ra[1], (int)rb[1]};
          const bf16x8 pB = u.h;
          __builtin_amdgcn_s_setprio(1);
#pragma unroll
          for (int db = 0; db < 4; db++) {
            const char* vp = (const char*)(Vs[cur]) + (db * 32 + q32) * 128;
            bf16x8 vf = *(const bf16x8*)(vp + ((half * 64 + 0 + 16 * hf) ^ swz));
            of[db] = __builtin_amdgcn_mfma_f32_32x32x16_bf16(vf, pB, of[db], 0, 0, 0);
          }
          __builtin_amdgcn_s_setprio(0);
        }
        {
          auto rc = __builtin_amdgcn_permlane32_swap(wv[4], wv[6], false, false);
          auto rd = __builtin_amdgcn_permlane32_swap(wv[5], wv[7], false, false);
          union { int4v i; bf16x8 h; } u2;
          u2.i = (int4v){(int)rc[0], (int)rd[0], (int)rc[1], (int)rd[1]};
          const bf16x8 pB = u2.h;
          __builtin_amdgcn_s_setprio(1);
#pragma unroll
          for (int db = 0; db < 4; db++) {
            const char* vp = (const char*)(Vs[cur]) + (db * 32 + q32) * 128;
            bf16x8 vf = *(const bf16x8*)(vp + ((half * 64 + 32 + 16 * hf) ^ swz));
            of[db] = __builtin_amdgcn_mfma_f32_32x32x16_bf16(vf, pB, of[db], 0, 0, 0);
          }
          __builtin_amdgcn_s_setprio(0);
        }
      }
    }
    if (t + 1 < ntiles) __syncthreads();
  }

  const float ltot = lsum + __shfl_xor(lsum, 32);
  unsigned short* AOu = (unsigned short*)AO;
  const float inv = 1.0f / ltot;
  const size_t rowb = (size_t)(b * SEQ + qw + q32) * HID + head * HD;
#pragma unroll
  for (int db = 0; db < 4; db++) {
#pragma unroll
    for (int qd = 0; qd < 4; qd++) {
      ushort4 o;
      o.x = f2bf(of[db][4 * qd + 0] * inv);
      o.y = f2bf(of[db][4 * qd + 1] * inv);
      o.z = f2bf(of[db][4 * qd + 2] * inv);
      o.w = f2bf(of[db][4 * qd + 3] * inv);
      *(ushort4*)&AOu[rowb + db * 32 + 8 * qd + 4 * hf] = o;
    }
  }
}

// ---------------------------------------------------------------------------
extern "C" void kernel_launch(void* const* d_in, const int* in_sizes, int n_in,
                              void* d_out, int out_size, void* d_ws, size_t ws_size,
                              hipStream_t stream) {
  const float* hs = (const float*)d_in[0];
  const float* cosb = (const float*)d_in[1];
  const float* sinb = (const float*)d_in[2];
  const float* Wq = (const float*)d_in[3];
  const float* bq = (const float*)d_in[4];
  const float* Wk = (const float*)d_in[5];
  const float* bk = (const float*)d_in[6];
  const float* Wv = (const float*)d_in[7];
  const float* bv = (const float*)d_in[8];
  const float* Wo = (const float*)d_in[9];

  char* ws = (char*)d_ws;
  __hip_bfloat16* Xb = (__hip_bfloat16*)(ws);
  __hip_bfloat16* Wcat = (__hip_bfloat16*)(ws + 29360128);
  float* bcat = (float*)(ws + 62390272);
  __hip_bfloat16* QKVb = (__hip_bfloat16*)(ws + 62408704);
  __hip_bfloat16* Vt = (__hip_bfloat16*)(ws + 100157440);
  __hip_bfloat16* AOb = Xb;    // X dead after projections
  __hip_bfloat16* Wob = Wcat;  // Wq/Wk rows dead after QK GEMM

  // Fused conversions (X, Wq, Wk, Wv) + bias concat (tail blocks)
  cvt_fused<<<30482, 256, 0, stream>>>(hs, Wq, Wk, Wv, bq, bk, bv, Xb, Wcat, bcat);

  // QK projection: [4096 x 4096] -> QKVb cols 0..4095. 256 blocks = 1 round.
  gemm256<true, true><<<256, 512, 0, stream>>>(Xb, Wcat, bcat, QKVb,
                                               4096, 4096, HID, 16, NQKV);

  // V projection (128 blocks) + RoPE (8192 blocks), one launch.
  vproj_rope<<<8320, 256, 0, stream>>>(Xb, Wcat + (size_t)4096 * 3584,
                                       bcat + 4096, QKVb, cosb, sinb);

  // V transpose (256 blocks) + Wo conversion, one launch.
  vt_wocvt<<<12800, 256, 0, stream>>>(QKVb, Vt, Wo, Wob);

  // Flash attention
  dim3 ga(56, 16);
  attn_fwd<<<ga, 256, 0, stream>>>(QKVb, Vt, AOb);

  // O projection -> f32 out (224 blocks; nnt=14 -> whole-m-row XCD chunks)
  gemm256<false, false><<<224, 512, 0, stream>>>(AOb, Wob, nullptr, d_out,
                                                 4096, HID, HID, 14, HID);
}

// Round 24
// 439.553 us; speedup vs baseline: 1.0126x; 1.0012x over previous
//
#include <hip/hip_runtime.h>
#include <hip/hip_bf16.h>

// Qwen2 attention layer, MI355X/gfx950.
// B=2 S=2048 HID=3584 NH=28 NKV=4 D=128, causal, GQA groups=7.
// Round 24 = round 23 (440.1 us, verified best) + Wo-cvt moved one launch
// earlier: it only needs {Wo, Wob-alias region dead after QK}, so it rides
// with vproj_rope (launch 3) instead of serializing in launch 4. Launch 4
// is now the tiny 256-block V-transpose only.
// All kernel bodies (gemm256 / attn / vproj / rope / vt) identical to r23.
//
// Workspace layout (bytes), total ~99.5 MB:
//   Xb    @ 0          29,360,128  (B*S x HID bf16)      -> reused as AOb
//   Wcat  @ 29,360,128 33,030,144  (4608 x 3584 bf16)    -> reused as Wo-bf16
//   bcat  @ 62,390,272 18,432      (4608 f32)
//   QKVb  @ 62,408,704 37,748,736  (B*S x 4608 bf16)
//   Vt    @ 100,157,440 4,194,304  (B*NKV*128 x S bf16)

#define HID   3584
#define NHQ   28
#define NKVH  4
#define HD    128
#define SEQ   2048
#define NQKV  4608
#define GRP   7

typedef __attribute__((ext_vector_type(8))) short bf16x8;
typedef __attribute__((ext_vector_type(4))) float f32x4;
typedef __attribute__((ext_vector_type(16))) float f32x16;
typedef __attribute__((ext_vector_type(4))) int int4v;

#define BARRIER() asm volatile("s_barrier" ::: "memory")
#define LGKM0_FENCE() do { \
    asm volatile("s_waitcnt lgkmcnt(0)" ::: "memory"); \
    __builtin_amdgcn_sched_barrier(0); \
  } while (0)

__device__ __forceinline__ void gload_lds16(const void* g, void* l) {
  __builtin_amdgcn_global_load_lds(
      (const __attribute__((address_space(1))) void*)g,
      (__attribute__((address_space(3))) void*)l, 16, 0, 0);
}

__device__ __forceinline__ unsigned short f2bf(float f) {
  __hip_bfloat16 h = __float2bfloat16(f);
  return *reinterpret_cast<unsigned short*>(&h);
}

__device__ __forceinline__ float bf2f(unsigned short u) {
  __hip_bfloat16 h = *reinterpret_cast<__hip_bfloat16*>(&u);
  return __bfloat162float(h);
}

// ------ fused f32->bf16 conversion (X, Wq, Wk, Wv) + bias concat -----------
__global__ __launch_bounds__(256)
void cvt_fused(const float* __restrict__ X, const float* __restrict__ Wq,
               const float* __restrict__ Wk, const float* __restrict__ Wv,
               const float* __restrict__ bq, const float* __restrict__ bk,
               const float* __restrict__ bv,
               __hip_bfloat16* __restrict__ Xb, __hip_bfloat16* __restrict__ Wcat,
               float* __restrict__ bcat) {
  if (blockIdx.x >= 30464) {   // bias tail: 18 blocks
    int i = (blockIdx.x - 30464) * 256 + threadIdx.x;
    if (i < HID) bcat[i] = bq[i];
    else if (i < HID + 512) bcat[i] = bk[i - HID];
    else if (i < NQKV) bcat[i] = bv[i - HID - 512];
    return;
  }
  int i = blockIdx.x * 256 + threadIdx.x;   // 0 .. 7,798,783 (f32x4 units)
  const float* src;
  __hip_bfloat16* dst;
  int off;
  if (i < 3670016)      { src = X;  dst = Xb;   off = i; }
  else if (i < 6881280) { src = Wq; dst = Wcat; off = i - 3670016; }
  else if (i < 7340032) { src = Wk; dst = Wcat + (size_t)3584 * 3584; off = i - 6881280; }
  else                  { src = Wv; dst = Wcat + (size_t)4096 * 3584; off = i - 7340032; }
  float4 v = ((const float4*)src)[off];
  ushort4 o;
  o.x = f2bf(v.x); o.y = f2bf(v.y); o.z = f2bf(v.z); o.w = f2bf(v.w);
  ((ushort4*)dst)[off] = o;
}

// ---------------- GEMM 256^2 (r23 body, unchanged) -------------------------
template<bool HAS_BIAS, bool OUT_BF16>
__global__ __launch_bounds__(512, 2)
void gemm256(const __hip_bfloat16* __restrict__ A, const __hip_bfloat16* __restrict__ Bm,
             const float* __restrict__ bias, void* __restrict__ Cv,
             int M, int N, int K, int nnt, int ldc) {
  __shared__ __align__(16) char lds[131072];
  const int tid = threadIdx.x;
  const int w = tid >> 6, l = tid & 63;
  const int g = l >> 4, r = l & 15;
  const int wr = w >> 2, wc = w & 3;

  const int nwg = gridDim.x;
  const int qq = nwg >> 3, r8 = nwg & 7;
  const int xcd = blockIdx.x & 7, idx = blockIdx.x >> 3;
  const int wgid = (xcd < r8 ? xcd * (qq + 1) : r8 * (qq + 1) + (xcd - r8) * qq) + idx;
  const int bn = (wgid % nnt) * 256, bm = (wgid / nnt) * 256;

  const int NKT = K >> 6;
  const size_t Kb2 = (size_t)K * 2;
  const int swz = (r & 7) << 4;

  auto issueHalf = [&](int kt, int h) {
    const char* src = (h < 2) ? (const char*)A : (const char*)Bm;
    const int rbase = (h < 2) ? bm : bn;
    char* reg = lds + (kt & 1) * 65536 + ((h < 2) ? 0 : 32768);
#pragma unroll
    for (int i = 0; i < 2; ++i) {
      const int lrow = (h & 1) * 128 + w * 16 + i * 8;
      const int row = lrow + (l >> 3);
      const int cb = (l & 7) * 16;
      gload_lds16(src + (size_t)(rbase + row) * Kb2 + (size_t)kt * 128 + (cb ^ ((row & 7) << 4)),
                  reg + lrow * 128);
    }
  };

  auto ldA = [&](int d, int mf, int kk) -> bf16x8 {
    const int row = wr * 128 + mf * 16 + r;
    return *(const bf16x8*)(lds + d * 65536 + row * 128 + ((kk * 64 + g * 16) ^ swz));
  };
  auto ldB = [&](int d, int nf, int kk) -> bf16x8 {
    const int row = wc * 64 + nf * 16 + r;
    return *(const bf16x8*)(lds + d * 65536 + 32768 + row * 128 + ((kk * 64 + g * 16) ^ swz));
  };

  f32x4 acc[8][4];
#pragma unroll
  for (int m = 0; m < 8; m++)
#pragma unroll
    for (int n = 0; n < 4; n++) acc[m][n] = (f32x4){0.f, 0.f, 0.f, 0.f};

#pragma unroll
  for (int h = 0; h < 4; ++h) issueHalf(0, h);
#pragma unroll
  for (int h = 0; h < 4; ++h) issueHalf(1, h);
  asm volatile("s_waitcnt vmcnt(8)" ::: "memory");
  BARRIER();

  bf16x8 af[4][2], bfr[4][2];

#pragma unroll 1
  for (int kt = 0; kt < NKT; ++kt) {
    const int d = kt & 1;

    if (kt >= 1 && kt + 1 < NKT) { issueHalf(kt + 1, 1); issueHalf(kt + 1, 3); }
#pragma unroll
    for (int mf = 0; mf < 4; mf++)
#pragma unroll
      for (int kk = 0; kk < 2; kk++) af[mf][kk] = ldA(d, mf, kk);
#pragma unroll
    for (int nf = 0; nf < 2; nf++)
#pragma unroll
      for (int kk = 0; kk < 2; kk++) bfr[nf][kk] = ldB(d, nf, kk);
    BARRIER();
    LGKM0_FENCE();
    __builtin_amdgcn_s_setprio(1);
#pragma unroll
    for (int mf = 0; mf < 4; mf++)
#pragma unroll
      for (int nf = 0; nf < 2; nf++)
#pragma unroll
        for (int kk = 0; kk < 2; kk++)
          acc[mf][nf] = __builtin_amdgcn_mfma_f32_16x16x32_bf16(af[mf][kk], bfr[nf][kk], acc[mf][nf], 0, 0, 0);
    __builtin_amdgcn_s_setprio(0);
    BARRIER();

#pragma unroll
    for (int nf = 2; nf < 4; nf++)
#pragma unroll
      for (int kk = 0; kk < 2; kk++) bfr[nf][kk] = ldB(d, nf, kk);
    BARRIER();
    LGKM0_FENCE();
    __builtin_amdgcn_s_setprio(1);
#pragma unroll
    for (int mf = 0; mf < 4; mf++)
#pragma unroll
      for (int nf = 2; nf < 4; nf++)
#pragma unroll
        for (int kk = 0; kk < 2; kk++)
          acc[mf][nf] = __builtin_amdgcn_mfma_f32_16x16x32_bf16(af[mf][kk], bfr[nf][kk], acc[mf][nf], 0, 0, 0);
    __builtin_amdgcn_s_setprio(0);
    BARRIER();

    if (kt + 2 < NKT) issueHalf(kt + 2, 2);
#pragma unroll
    for (int mf = 0; mf < 4; mf++)
#pragma unroll
      for (int kk = 0; kk < 2; kk++) af[mf][kk] = ldA(d, mf + 4, kk);
    BARRIER();
    LGKM0_FENCE();
    __builtin_amdgcn_s_setprio(1);
#pragma unroll
    for (int mf = 0; mf < 4; mf++)
#pragma unroll
      for (int nf = 0; nf < 2; nf++)
#pragma unroll
        for (int kk = 0; kk < 2; kk++)
          acc[mf + 4][nf] = __builtin_amdgcn_mfma_f32_16x16x32_bf16(af[mf][kk], bfr[nf][kk], acc[mf + 4][nf], 0, 0, 0);
    __builtin_amdgcn_s_setprio(0);
    BARRIER();

    if (kt + 2 < NKT) {
      issueHalf(kt + 2, 0);
      asm volatile("s_waitcnt vmcnt(4)" ::: "memory");
    } else if (kt + 1 < NKT) {
      asm volatile("s_waitcnt vmcnt(0)" ::: "memory");
    }
    BARRIER();
    __builtin_amdgcn_s_setprio(1);
#pragma unroll
    for (int mf = 0; mf < 4; mf++)
#pragma unroll
      for (int nf = 2; nf < 4; nf++)
#pragma unroll
        for (int kk = 0; kk < 2; kk++)
          acc[mf + 4][nf] = __builtin_amdgcn_mfma_f32_16x16x32_bf16(af[mf][kk], bfr[nf][kk], acc[mf + 4][nf], 0, 0, 0);
    __builtin_amdgcn_s_setprio(0);
    BARRIER();
  }

#pragma unroll
  for (int nf = 0; nf < 4; nf++) {
    const int gcol = bn + wc * 64 + nf * 16 + r;
    const float bv = HAS_BIAS ? bias[gcol] : 0.f;
#pragma unroll
    for (int mf = 0; mf < 8; mf++) {
#pragma unroll
      for (int j = 0; j < 4; j++) {
        const int grow = bm + wr * 128 + mf * 16 + 4 * g + j;
        float v = acc[mf][nf][j] + bv;
        if constexpr (OUT_BF16)
          ((__hip_bfloat16*)Cv)[(size_t)grow * ldc + gcol] = __float2bfloat16(v);
        else
          ((float*)Cv)[(size_t)grow * ldc + gcol] = v;
      }
    }
  }
}

// ------ V-projection + RoPE + Wo conversion, fused one launch --------------
// Blocks 0..127: V-proj. 128..8319: rope. 8320..20863: Wo cvt (Wob aliases
// Wq/Wk rows of Wcat, dead after QK-proj which completed in launch 2).
__global__ __launch_bounds__(256)
void vproj_rope(const __hip_bfloat16* __restrict__ Xb, const __hip_bfloat16* __restrict__ Wv_b,
                const float* __restrict__ bias_v, __hip_bfloat16* __restrict__ QKVb,
                const float* __restrict__ cosb, const float* __restrict__ sinb,
                const float* __restrict__ Wo, __hip_bfloat16* __restrict__ Wob) {
  __shared__ __align__(16) __hip_bfloat16 As[128 * 32];
  __shared__ __align__(16) __hip_bfloat16 Bs[128 * 32];
  if (blockIdx.x < 128) {
    const int tid = threadIdx.x;
    const int w = tid >> 6, l = tid & 63;
    const int g = l >> 4, r = l & 15;
    const int wr = w >> 1, wc = w & 1;
    const int bm = (blockIdx.x & 31) * 128;
    const int bn = (blockIdx.x >> 5) * 128;
    const int lr = l >> 2;
    const int lc = (l & 3) * 8;

    f32x4 acc[4][4];
#pragma unroll
    for (int m = 0; m < 4; m++)
#pragma unroll
      for (int n = 0; n < 4; n++) acc[m][n] = (f32x4){0.f, 0.f, 0.f, 0.f};

    for (int k0 = 0; k0 < HID; k0 += 32) {
#pragma unroll
      for (int i = 0; i < 2; i++) {
        const int rb = w * 32 + i * 16;
        gload_lds16(&Xb[(size_t)(bm + rb + lr) * HID + k0 + lc], &As[rb * 32]);
        gload_lds16(&Wv_b[(size_t)(bn + rb + lr) * HID + k0 + lc], &Bs[rb * 32]);
      }
      __syncthreads();
      bf16x8 af[4], bfr[4];
#pragma unroll
      for (int m = 0; m < 4; m++) af[m] = *(const bf16x8*)&As[(wr * 64 + m * 16 + r) * 32 + g * 8];
#pragma unroll
      for (int n = 0; n < 4; n++) bfr[n] = *(const bf16x8*)&Bs[(wc * 64 + n * 16 + r) * 32 + g * 8];
#pragma unroll
      for (int m = 0; m < 4; m++)
#pragma unroll
        for (int n = 0; n < 4; n++)
          acc[m][n] = __builtin_amdgcn_mfma_f32_16x16x32_bf16(af[m], bfr[n], acc[m][n], 0, 0, 0);
      __syncthreads();
    }

#pragma unroll
    for (int m = 0; m < 4; m++) {
#pragma unroll
      for (int n = 0; n < 4; n++) {
        const int gcol = bn + wc * 64 + n * 16 + r;
        const float bv = bias_v[gcol];
#pragma unroll
        for (int j = 0; j < 4; j++) {
          const int grow = bm + wr * 64 + m * 16 + 4 * g + j;
          QKVb[(size_t)grow * NQKV + 4096 + gcol] = __float2bfloat16(acc[m][n][j] + bv);
        }
      }
    }
  } else if (blockIdx.x < 8320) {
    int i = (blockIdx.x - 128) * 256 + threadIdx.x;
    int d = (i & 15) * 4;
    int hh = (i >> 4) & 31;
    int row = i >> 9;
    int cb = (hh < NHQ) ? hh * HD : HID + (hh - NHQ) * HD;
    const float qs = (hh < NHQ) ? 0.12751744055204955f : 1.0f;
    unsigned short* base = (unsigned short*)QKVb + (size_t)row * NQKV + cb;
    float4 c = *(const float4*)&cosb[row * HD + d];
    float4 sn = *(const float4*)&sinb[row * HD + d];
    ushort4 u1 = *(const ushort4*)(base + d);
    ushort4 u2 = *(const ushort4*)(base + d + 64);
    float x1[4] = {bf2f(u1.x), bf2f(u1.y), bf2f(u1.z), bf2f(u1.w)};
    float x2[4] = {bf2f(u2.x), bf2f(u2.y), bf2f(u2.z), bf2f(u2.w)};
    float cc[4] = {c.x, c.y, c.z, c.w};
    float ss[4] = {sn.x, sn.y, sn.z, sn.w};
    ushort4 o1, o2;
    o1.x = f2bf((x1[0] * cc[0] - x2[0] * ss[0]) * qs); o2.x = f2bf((x2[0] * cc[0] + x1[0] * ss[0]) * qs);
    o1.y = f2bf((x1[1] * cc[1] - x2[1] * ss[1]) * qs); o2.y = f2bf((x2[1] * cc[1] + x1[1] * ss[1]) * qs);
    o1.z = f2bf((x1[2] * cc[2] - x2[2] * ss[2]) * qs); o2.z = f2bf((x2[2] * cc[2] + x1[2] * ss[2]) * qs);
    o1.w = f2bf((x1[3] * cc[3] - x2[3] * ss[3]) * qs); o2.w = f2bf((x2[3] * cc[3] + x1[3] * ss[3]) * qs);
    *(ushort4*)(base + d) = o1;
    *(ushort4*)(base + d + 64) = o2;
  } else {
    int off = (blockIdx.x - 8320) * 256 + threadIdx.x;   // < 3,211,264
    float4 v = ((const float4*)Wo)[off];
    ushort4 o;
    o.x = f2bf(v.x); o.y = f2bf(v.y); o.z = f2bf(v.z); o.w = f2bf(v.w);
    ((ushort4*)Wob)[off] = o;
  }
}

// ------ V transpose (LDS-tiled) ---------------------------------------------
__global__ __launch_bounds__(256)
void v_tr(const __hip_bfloat16* __restrict__ QKV, __hip_bfloat16* __restrict__ Vt) {
  __shared__ ushort tile[64][136];
  const int bx = blockIdx.x;
  const int st = bx & 31, kv = (bx >> 5) & 3, b = bx >> 7;
  const int s0 = st * 64;
  const int t = threadIdx.x;
  const int sl = t >> 4, dv = (t & 15) * 8;
  const ushort* src = (const ushort*)QKV + (size_t)(b * SEQ) * NQKV + HID + 512 + kv * HD;
#pragma unroll
  for (int p = 0; p < 4; p++) {
    const int s = s0 + p * 16 + sl;
    *(uint4*)&tile[p * 16 + sl][dv] = *(const uint4*)&src[(size_t)s * NQKV + dv];
  }
  __syncthreads();
  ushort* dst = (ushort*)Vt + (size_t)((b * NKVH + kv) * HD) * SEQ;
#pragma unroll
  for (int it = 0; it < 8; it++) {
    const int idx = it * 256 + t;
    const int d = idx >> 4, sg = idx & 15;
    ushort4 o;
    o.x = tile[sg * 4 + 0][d];
    o.y = tile[sg * 4 + 1][d];
    o.z = tile[sg * 4 + 2][d];
    o.w = tile[sg * 4 + 3][d];
    *(ushort4*)&dst[(size_t)d * SEQ + s0 + sg * 4] = o;
  }
}

// ---------------- Flash attention (r23 body, unchanged) --------------------
__global__ __launch_bounds__(256, 2)
void attn_fwd(const __hip_bfloat16* __restrict__ QKV, const __hip_bfloat16* __restrict__ Vt,
              __hip_bfloat16* __restrict__ AO) {
  const int head = blockIdx.x >> 1;
  const int b = blockIdx.x & 1;
  const int qb = 15 - blockIdx.y;           // LPT
  const int kvh = head / GRP;
  const int tid = threadIdx.x;
  const int w = tid >> 6, l = tid & 63;
  const int q32 = l & 31;
  const int hf = l >> 5;
  const int qw = qb * 128 + w * 32;
  const float NEGINF = -__builtin_inff();

  __shared__ __align__(16) __hip_bfloat16 Ks[2][64 * 128];
  __shared__ __align__(16) __hip_bfloat16 Vs[2][128 * 64];

  const char* Kb = (const char*)(QKV + (size_t)(b * SEQ) * NQKV + HID + kvh * HD);
  const char* Vb = (const char*)(Vt + (size_t)((b * NKVH + kvh) * HD) * SEQ);
  const __hip_bfloat16* Qb = QKV + (size_t)(b * SEQ + qw) * NQKV + head * HD;

  bf16x8 qf[8];
#pragma unroll
  for (int c = 0; c < 8; c++)
    qf[c] = *(const bf16x8*)&Qb[(size_t)q32 * NQKV + c * 16 + 8 * hf];

  f32x16 of[4] = {};
  float mrow = -3e38f, lsum = 0.f;

  const int ntiles = 2 * qb + 2;

  auto stage = [&](int buf, int kv0) {
#pragma unroll
    for (int p = 0; p < 4; p++) {
      const int row = w * 16 + p * 4 + (l >> 4);
      const int cb = (l & 15) * 16;
      gload_lds16(Kb + (size_t)(kv0 + row) * (NQKV * 2) + (cb ^ ((row & 7) << 4)),
                  (char*)(Ks[buf]) + w * 4096 + p * 1024);
    }
#pragma unroll
    for (int p = 0; p < 4; p++) {
      const int row = w * 32 + p * 8 + (l >> 3);
      const int cb = (l & 7) * 16;
      gload_lds16(Vb + (size_t)row * (SEQ * 2) + (size_t)kv0 * 2 + (cb ^ ((row & 7) << 4)),
                  (char*)(Vs[buf]) + w * 4096 + p * 1024);
    }
  };

  stage(0, 0);
  __syncthreads();

  const int swz = (q32 & 7) << 4;
  const int qg = qw + q32;

  for (int t = 0; t < ntiles; t++) {
    const int cur = t & 1;
    if (t + 1 < ntiles) stage(cur ^ 1, t * 64 + 64);

#pragma unroll
    for (int half = 0; half < 2; half++) {
      const int kv0 = t * 64 + half * 32;
      if (kv0 <= qw + 31) {
        f32x16 s = {};
        const char* kb = (const char*)(Ks[cur]) + (half * 32 + q32) * 256;
        __builtin_amdgcn_s_setprio(1);
#pragma unroll
        for (int c = 0; c < 8; c++) {
          bf16x8 kf = *(const bf16x8*)(kb + ((c * 32 + 16 * hf) ^ swz));
          s = __builtin_amdgcn_mfma_f32_32x32x16_bf16(kf, qf[c], s, 0, 0, 0);
        }
        __builtin_amdgcn_s_setprio(0);

        if (!(kv0 + 31 <= qw)) {
#pragma unroll
          for (int j = 0; j < 16; j++) {
            const int kvl = (j & 3) + 8 * (j >> 2) + 4 * hf;
            s[j] = (kv0 + kvl <= qg) ? s[j] : NEGINF;
          }
        }
        float m0 = fmaxf(s[0], s[4]), m1 = fmaxf(s[1], s[5]);
        float m2 = fmaxf(s[2], s[6]), m3 = fmaxf(s[3], s[7]);
        m0 = fmaxf(m0, fmaxf(s[8], s[12]));  m1 = fmaxf(m1, fmaxf(s[9], s[13]));
        m2 = fmaxf(m2, fmaxf(s[10], s[14])); m3 = fmaxf(m3, fmaxf(s[11], s[15]));
        float pmax = fmaxf(fmaxf(m0, m1), fmaxf(m2, m3));
        pmax = fmaxf(pmax, __shfl_xor(pmax, 32));

        float rs = 0.f;
        if (__all(pmax - mrow <= 11.5f)) {
#pragma unroll
          for (int j = 0; j < 16; j++) { float p = exp2f(s[j] - mrow); s[j] = p; rs += p; }
        } else {
          const float nm = fmaxf(mrow, pmax);
          const float al = exp2f(mrow - nm);
          mrow = nm;
#pragma unroll
          for (int j = 0; j < 16; j++) { float p = exp2f(s[j] - nm); s[j] = p; rs += p; }
          lsum *= al;
#pragma unroll
          for (int db = 0; db < 4; db++) of[db] *= al;
        }
        lsum += rs;

        int wv[8];
#pragma unroll
        for (int k = 0; k < 8; k++)
          wv[k] = (int)((unsigned)f2bf(s[2 * k]) | ((unsigned)f2bf(s[2 * k + 1]) << 16));

        {
          auto ra = __builtin_amdgcn_permlane32_swap(wv[0], wv[2], false, false);
          auto rb = __builtin_amdgcn_permlane32_swap(wv[1], wv[3], false, false);
          union { int4v i; bf16x8 h; } u;
          u.i = (int4v){(int)ra[0], (int)rb[0], (int)ra[1], (int)rb[1]};
          const bf16x8 pB = u.h;
          __builtin_amdgcn_s_setprio(1);
#pragma unroll
          for (int db = 0; db < 4; db++) {
            const char* vp = (const char*)(Vs[cur]) + (db * 32 + q32) * 128;
            bf16x8 vf = *(const bf16x8*)(vp + ((half * 64 + 0 + 16 * hf) ^ swz));
            of[db] = __builtin_amdgcn_mfma_f32_32x32x16_bf16(vf, pB, of[db], 0, 0, 0);
          }
          __builtin_amdgcn_s_setprio(0);
        }
        {
          auto rc = __builtin_amdgcn_permlane32_swap(wv[4], wv[6], false, false);
          auto rd = __builtin_amdgcn_permlane32_swap(wv[5], wv[7], false, false);
          union { int4v i; bf16x8 h; } u2;
          u2.i = (int4v){(int)rc[0], (int)rd[0], (int)rc[1], (int)rd[1]};
          const bf16x8 pB = u2.h;
          __builtin_amdgcn_s_setprio(1);
#pragma unroll
          for (int db = 0; db < 4; db++) {
            const char* vp = (const char*)(Vs[cur]) + (db * 32 + q32) * 128;
            bf16x8 vf = *(const bf16x8*)(vp + ((half * 64 + 32 + 16 * hf) ^ swz));
            of[db] = __builtin_amdgcn_mfma_f32_32x32x16_bf16(vf, pB, of[db], 0, 0, 0);
          }
          __builtin_amdgcn_s_setprio(0);
        }
      }
    }
    if (t + 1 < ntiles) __syncthreads();
  }

  const float ltot = lsum + __shfl_xor(lsum, 32);
  unsigned short* AOu = (unsigned short*)AO;
  const float inv = 1.0f / ltot;
  const size_t rowb = (size_t)(b * SEQ + qw + q32) * HID + head * HD;
#pragma unroll
  for (int db = 0; db < 4; db++) {
#pragma unroll
    for (int qd = 0; qd < 4; qd++) {
      ushort4 o;
      o.x = f2bf(of[db][4 * qd + 0] * inv);
      o.y = f2bf(of[db][4 * qd + 1] * inv);
      o.z = f2bf(of[db][4 * qd + 2] * inv);
      o.w = f2bf(of[db][4 * qd + 3] * inv);
      *(ushort4*)&AOu[rowb + db * 32 + 8 * qd + 4 * hf] = o;
    }
  }
}

// ---------------------------------------------------------------------------
extern "C" void kernel_launch(void* const* d_in, const int* in_sizes, int n_in,
                              void* d_out, int out_size, void* d_ws, size_t ws_size,
                              hipStream_t stream) {
  const float* hs = (const float*)d_in[0];
  const float* cosb = (const float*)d_in[1];
  const float* sinb = (const float*)d_in[2];
  const float* Wq = (const float*)d_in[3];
  const float* bq = (const float*)d_in[4];
  const float* Wk = (const float*)d_in[5];
  const float* bk = (const float*)d_in[6];
  const float* Wv = (const float*)d_in[7];
  const float* bv = (const float*)d_in[8];
  const float* Wo = (const float*)d_in[9];

  char* ws = (char*)d_ws;
  __hip_bfloat16* Xb = (__hip_bfloat16*)(ws);
  __hip_bfloat16* Wcat = (__hip_bfloat16*)(ws + 29360128);
  float* bcat = (float*)(ws + 62390272);
  __hip_bfloat16* QKVb = (__hip_bfloat16*)(ws + 62408704);
  __hip_bfloat16* Vt = (__hip_bfloat16*)(ws + 100157440);
  __hip_bfloat16* AOb = Xb;    // X dead after projections
  __hip_bfloat16* Wob = Wcat;  // Wq/Wk rows dead after QK GEMM

  // Fused conversions (X, Wq, Wk, Wv) + bias concat (tail blocks)
  cvt_fused<<<30482, 256, 0, stream>>>(hs, Wq, Wk, Wv, bq, bk, bv, Xb, Wcat, bcat);

  // QK projection: [4096 x 4096] -> QKVb cols 0..4095. 256 blocks = 1 round.
  gemm256<true, true><<<256, 512, 0, stream>>>(Xb, Wcat, bcat, QKVb,
                                               4096, 4096, HID, 16, NQKV);

  // V projection (128) + RoPE (8192) + Wo cvt (12544), one launch.
  vproj_rope<<<20864, 256, 0, stream>>>(Xb, Wcat + (size_t)4096 * 3584,
                                        bcat + 4096, QKVb, cosb, sinb, Wo, Wob);

  // V transpose only (256 blocks).
  v_tr<<<256, 256, 0, stream>>>(QKVb, Vt);

  // Flash attention
  dim3 ga(56, 16);
  attn_fwd<<<ga, 256, 0, stream>>>(QKVb, Vt, AOb);

  // O projection -> f32 out (224 blocks; nnt=14 -> whole-m-row XCD chunks)
  gemm256<false, false><<<224, 512, 0, stream>>>(AOb, Wob, nullptr, d_out,
                                                 4096, HID, HID, 14, HID);
}